// Round 1
// 655.298 us; speedup vs baseline: 1.3208x; 1.3208x over previous
//
#include <hip/hip_runtime.h>

#define SEQ 14
#define EMB 64
#define NBC (1024*64)      // B*C = 65536
#define XTILE (SEQ*EMB)    // 896 floats per (b,c) tile
#define LN_EPS 1e-5f
#define WAVES 4
#define XSTR 68            // padded LDS row stride for x/g tiles
#define ESTR 18            // padded LDS row stride for energy/att tile

// ---------------------------------------------------------------------------
// prep: M[d][e] = sum_t Wq[t][d]*Wk[t][e]   (so energy = x M x^T + ...)
//       WvT[d][e] = Wv[e][d]
//       r[e] = sum_t bq[t]*Wk[t][e]         (bk-terms cancel under LayerNorm)
// ws layout (floats): interleaved MW[d][e] = (M, WvT) pairs: 64*64*2 = 8192,
//                     then r at [8192..8255]
// ---------------------------------------------------------------------------
__global__ void prep_kernel(const float* __restrict__ Wq, const float* __restrict__ Wk,
                            const float* __restrict__ Wv, const float* __restrict__ bq,
                            float* __restrict__ ws) {
    int d = blockIdx.x;    // 0..63
    int e = threadIdx.x;   // 0..63
    float m = 0.f, r = 0.f;
#pragma unroll 8
    for (int t = 0; t < 64; ++t) {
        float wk = Wk[t*64 + e];
        m = fmaf(Wq[t*64 + d], wk, m);
        r = fmaf(bq[t], wk, r);
    }
    ws[d*128 + 2*e]     = m;               // M[d][e]
    ws[d*128 + 2*e + 1] = Wv[e*64 + d];    // WvT[d][e]
    if (d == 0) ws[8192 + e] = r;
}

// ---------------------------------------------------------------------------
// main: one wave per (b,c) pair, grid-stride.
// v2 changes vs 864us baseline:
//   - M/WvT no longer staged in LDS (was 32 KB/block): read from global per
//     bc (32 KB, identical for all waves -> L1/L2 resident). LDS drops
//     66.5 KB -> ~35 KB => 4 blocks/CU => 16 waves/CU (was 8).
//   - __launch_bounds__(256,4): cap VGPR at 128 for 4 waves/SIMD.
//   - phase D parallelized over 56 lanes (4 lanes/row, shfl_xor reductions).
//   - next-tile prefetch issued after phase A's weight loads (no forced
//     early vmcnt drain of the HBM prefetch).
// ---------------------------------------------------------------------------
__global__ __launch_bounds__(256, 4)
void attn_kernel(const float* __restrict__ x, const float* __restrict__ wc,
                 const float* __restrict__ bv, const float* __restrict__ lng,
                 const float* __restrict__ lnb, const float* __restrict__ ws,
                 float* __restrict__ out) {
    __shared__ __align__(16) float Lwc[14*16];           // w_c rows, stride 16, zero-pad
    __shared__ __align__(16) float Lln[2*16];            // ln_g, ln_b
    __shared__ __align__(16) float LxW[WAVES][SEQ*XSTR]; // per-wave x tile [q][d]
    __shared__ __align__(16) float LgW[WAVES][SEQ*XSTR]; // per-wave g tile [a][d]
    __shared__ __align__(16) float LeW[WAVES][SEQ*ESTR]; // per-wave energy1/att [a][l]

    int tid = threadIdx.x;

    if (tid < 224) {
        int a = tid >> 4, m = tid & 15;
        Lwc[tid] = (m < 14) ? wc[a*14 + m] : 0.f;
    }
    if (tid < 16) {
        Lln[tid]      = (tid < 14) ? lng[tid] : 0.f;
        Lln[16 + tid] = (tid < 14) ? lnb[tid] : 0.f;
    }
    __syncthreads();   // only block barrier in the kernel

    int lane = tid & 63;
    int wv   = __builtin_amdgcn_readfirstlane(tid >> 6);
    int wv0  = blockIdx.x * WAVES + wv;
    const int TW = gridDim.x * WAVES;

    float rv  = ws[8192 + lane];   // r[e]
    float bvv = bv[lane];          // v bias

    float* xw = &LxW[wv][0];
    float* gw = &LgW[wv][0];
    float* ew = &LeW[wv][0];

    // ---- phase-C work assignment, hoisted out of the bc loop ----
    int ewo[4], gao[4], xlo[4];
#pragma unroll
    for (int k = 0; k < 4; ++k) {
        int p = lane + 64*k;
        int a = p / 14, l = p - a*14;
        if (p >= 196) { a = 0; l = 0; }
        ewo[k] = a*ESTR + l;
        gao[k] = a*XSTR;
        xlo[k] = l*XSTR;
    }

    // LDS write addresses for the staged x tile (padded [q][d] layout)
    int i0 = lane, i1 = 64 + lane, i2 = 128 + lane, i3 = 192 + lane;
    float* w0 = xw + (i0 >> 4)*XSTR + (i0 & 15)*4;
    float* w1 = xw + (i1 >> 4)*XSTR + (i1 & 15)*4;
    float* w2 = xw + (i2 >> 4)*XSTR + (i2 & 15)*4;
    float* w3 = xw + (i3 >> 4)*XSTR + (i3 & 15)*4;

    // ---- prologue: prefetch first tile into registers ----
    float4 pf0, pf1, pf2, pf3;
    {
        const float4* xb4 = (const float4*)(x + (size_t)wv0 * XTILE);
        pf0 = xb4[i0];
        pf1 = xb4[i1];
        pf2 = xb4[i2];
        if (lane < 32) pf3 = xb4[i3];
    }

    for (int bc = wv0; bc < NBC; bc += TW) {
        // ---- commit prefetched tile to LDS ----
        *(float4*)w0 = pf0;
        *(float4*)w1 = pf1;
        *(float4*)w2 = pf2;
        if (lane < 32) *(float4*)w3 = pf3;

        // opaque copy of the weight pointer: defeat LICM hoisting the 64
        // in-loop weight loads across the bc loop (would need 128 VGPRs).
        const float* mws = ws;
        asm volatile("" : "+s"(mws));
        const float2* mw2 = (const float2*)mws;

        // ---- phase A: t'[i][lane] = x[i][:]·M[:][lane] + r
        //               v [i][lane] = x[i][:]·WvT[:][lane] + bv
        //      x broadcast from LDS, (M,WvT) float2 from global (L1/L2) ----
        float tc[SEQ], vcr[SEQ];
#pragma unroll
        for (int i = 0; i < SEQ; ++i) { tc[i] = rv; vcr[i] = bvv; }

#pragma unroll 2
        for (int d0 = 0; d0 < 16; ++d0) {
            float2 m0 = mw2[(d0*4 + 0)*64 + lane];
            float2 m1 = mw2[(d0*4 + 1)*64 + lane];
            float2 m2 = mw2[(d0*4 + 2)*64 + lane];
            float2 m3 = mw2[(d0*4 + 3)*64 + lane];
#pragma unroll
            for (int i = 0; i < SEQ; ++i) {
                float4 x4 = *(const float4*)(xw + i*XSTR + d0*4);   // broadcast
                tc[i]  = fmaf(x4.x, m0.x, tc[i]);  vcr[i] = fmaf(x4.x, m0.y, vcr[i]);
                tc[i]  = fmaf(x4.y, m1.x, tc[i]);  vcr[i] = fmaf(x4.y, m1.y, vcr[i]);
                tc[i]  = fmaf(x4.z, m2.x, tc[i]);  vcr[i] = fmaf(x4.z, m2.y, vcr[i]);
                tc[i]  = fmaf(x4.w, m3.x, tc[i]);  vcr[i] = fmaf(x4.w, m3.y, vcr[i]);
            }
        }

        // ---- prefetch next tile (issued after phase A's weight loads so
        //      their vmcnt waits never force-drain this prefetch) ----
        int bcn = bc + TW;
        if (bcn < NBC) {
            const float4* xn4 = (const float4*)(x + (size_t)bcn * XTILE);
            pf0 = xn4[i0];
            pf1 = xn4[i1];
            pf2 = xn4[i2];
            if (lane < 32) pf3 = xn4[i3];
        }

        // ---- phase B: g[a][lane] = sum_m wc[a][m] * t'[m][lane] ----
#pragma unroll
        for (int a = 0; a < SEQ; ++a) {
            const float* wr = Lwc + a*16;
            float4 wa = *(const float4*)(wr);
            float4 wb = *(const float4*)(wr + 4);
            float4 wcc = *(const float4*)(wr + 8);
            float2 wd = *(const float2*)(wr + 12);
            float acc;
            acc = wa.x * tc[0];
            acc = fmaf(wa.y,  tc[1],  acc);
            acc = fmaf(wa.z,  tc[2],  acc);
            acc = fmaf(wa.w,  tc[3],  acc);
            acc = fmaf(wb.x,  tc[4],  acc);
            acc = fmaf(wb.y,  tc[5],  acc);
            acc = fmaf(wb.z,  tc[6],  acc);
            acc = fmaf(wb.w,  tc[7],  acc);
            acc = fmaf(wcc.x, tc[8],  acc);
            acc = fmaf(wcc.y, tc[9],  acc);
            acc = fmaf(wcc.z, tc[10], acc);
            acc = fmaf(wcc.w, tc[11], acc);
            acc = fmaf(wd.x,  tc[12], acc);
            acc = fmaf(wd.y,  tc[13], acc);
            gw[a*XSTR + lane] = acc;
        }

        // ---- phase C: energy1[a][l] = g[a][:]·x[l][:] (196 dots) ----
#pragma unroll
        for (int k = 0; k < 4; ++k) {
            if (k < 3 || lane < 4) {     // k=0..2 fully active; k=3 lanes 0..3
                const float* gp = gw + gao[k];
                const float* xp = xw + xlo[k];
                float acc = 0.f;
#pragma unroll
                for (int d = 0; d < 64; d += 4) {
                    float4 g4 = *(const float4*)(gp + d);
                    float4 x4 = *(const float4*)(xp + d);
                    acc = fmaf(g4.x, x4.x, acc);
                    acc = fmaf(g4.y, x4.y, acc);
                    acc = fmaf(g4.z, x4.z, acc);
                    acc = fmaf(g4.w, x4.w, acc);
                }
                ew[ewo[k]] = acc;
            }
        }

        // ---- phase D: LayerNorm(14) + softmax, 4 lanes per row ----
        {
            int a = lane >> 2, s = lane & 3;
            if (lane < 56) {
                float* er = ew + a*ESTR;
                bool h3 = (s < 2);                  // s=0,1 own 4 elems; s=2,3 own 3
                float e0 = er[s], e1 = er[s+4], e2 = er[s+8];
                float e3 = h3 ? er[s+12] : 0.f;
                float sm = e0 + e1 + e2 + e3;
                sm += __shfl_xor(sm, 1);
                sm += __shfl_xor(sm, 2);
                float mu = sm * (1.f/14.f);
                float d0v = e0-mu, d1v = e1-mu, d2v = e2-mu, d3v = h3 ? (e3-mu) : 0.f;
                float vr = d0v*d0v;
                vr = fmaf(d1v, d1v, vr);
                vr = fmaf(d2v, d2v, vr);
                vr = fmaf(d3v, d3v, vr);
                vr += __shfl_xor(vr, 1);
                vr += __shfl_xor(vr, 2);
                float inv = rsqrtf(vr*(1.f/14.f) + LN_EPS);
                float z0 = fmaf(d0v*inv, Lln[s],    Lln[16+s])   * 0.125f;  // /sqrt(64)
                float z1 = fmaf(d1v*inv, Lln[s+4],  Lln[16+s+4]) * 0.125f;
                float z2 = fmaf(d2v*inv, Lln[s+8],  Lln[16+s+8]) * 0.125f;
                float z3 = h3 ? fmaf(d3v*inv, Lln[s+12], Lln[16+s+12]) * 0.125f : -1e30f;
                float zm = fmaxf(fmaxf(z0, z1), fmaxf(z2, z3));
                zm = fmaxf(zm, __shfl_xor(zm, 1));
                zm = fmaxf(zm, __shfl_xor(zm, 2));
                float p0 = __expf(z0 - zm), p1 = __expf(z1 - zm), p2 = __expf(z2 - zm);
                float p3 = h3 ? __expf(z3 - zm) : 0.f;
                float ssum = p0 + p1 + p2 + p3;
                ssum += __shfl_xor(ssum, 1);
                ssum += __shfl_xor(ssum, 2);
                float rs = 1.f / ssum;
                er[s]    = p0 * rs;
                er[s+4]  = p1 * rs;
                er[s+8]  = p2 * rs;
                if (h3) er[s+12] = p3 * rs;
            }
        }

        // ---- phase E: out[a][lane] = sum_l att[a][l] * v[l][lane] ----
        float* outb = out + (size_t)bc * XTILE;
#pragma unroll
        for (int a = 0; a < SEQ; ++a) {
            const float* er = ew + a*ESTR;
            float acc = 0.f;
#pragma unroll
            for (int l2 = 0; l2 < 7; ++l2) {
                float2 at2 = *(const float2*)(er + 2*l2);    // broadcast
                acc = fmaf(at2.x, vcr[2*l2],     acc);
                acc = fmaf(at2.y, vcr[2*l2 + 1], acc);
            }
            outb[a*64 + lane] = acc;
        }
    }
}

extern "C" void kernel_launch(void* const* d_in, const int* in_sizes, int n_in,
                              void* d_out, int out_size, void* d_ws, size_t ws_size,
                              hipStream_t stream) {
    (void)in_sizes; (void)n_in; (void)out_size; (void)ws_size;
    const float* x   = (const float*)d_in[0];
    const float* wc  = (const float*)d_in[1];
    const float* Wq  = (const float*)d_in[2];
    const float* bq  = (const float*)d_in[3];
    const float* Wk  = (const float*)d_in[4];
    // d_in[5] = bk: cancelled by LayerNorm mean-subtraction -> unused.
    const float* Wv  = (const float*)d_in[6];
    const float* bv  = (const float*)d_in[7];
    const float* lng = (const float*)d_in[8];
    const float* lnb = (const float*)d_in[9];
    float* out = (float*)d_out;
    float* ws  = (float*)d_ws;

    prep_kernel<<<dim3(64), dim3(64), 0, stream>>>(Wq, Wk, Wv, bq, ws);
    attn_kernel<<<dim3(2048), dim3(256), 0, stream>>>(x, wc, bv, lng, lnb, ws, out);
}